// Round 1
// baseline (336.760 us; speedup 1.0000x reference)
//
#include <hip/hip_runtime.h>

#define HH 56
#define WW 56
#define HW 3136          // 56*56
#define NV4 784          // HW/4
#define BLK 256

__global__ __launch_bounds__(BLK) void local_mask_kernel(
    const float* __restrict__ x, const int* __restrict__ T, float* __restrict__ out)
{
    const int ch  = blockIdx.x;
    const int tid = threadIdx.x;
    const float4* __restrict__ xin  = (const float4*)(x   + (size_t)ch * HW);
    float4* __restrict__       xout = (float4*)      (out + (size_t)ch * HW);

    // Load the whole plane into registers: 784 float4 over 256 threads.
    // Threads 0..15 do 4 iterations, the rest do 3 (i = tid + k*256 < 784).
    float4 v[4];
    #pragma unroll
    for (int k = 0; k < 4; ++k) {
        int i = tid + k * BLK;
        if (i < NV4) v[k] = xin[i];
    }

    const bool marked = (T[ch] > 0);   // block-uniform
    if (!marked) {
        // Straight copy.
        #pragma unroll
        for (int k = 0; k < 4; ++k) {
            int i = tid + k * BLK;
            if (i < NV4) xout[i] = v[k];
        }
        return;
    }

    // ---- per-thread argmax (ascending indices => first-index tie-break) ----
    float bestv = -__builtin_inff();
    int   besti = 0;
    #pragma unroll
    for (int k = 0; k < 4; ++k) {
        int i = tid + k * BLK;
        if (i < NV4) {
            const float4 f = v[k];
            const int base = i * 4;
            if (f.x > bestv) { bestv = f.x; besti = base;     }
            if (f.y > bestv) { bestv = f.y; besti = base + 1; }
            if (f.z > bestv) { bestv = f.z; besti = base + 2; }
            if (f.w > bestv) { bestv = f.w; besti = base + 3; }
        }
    }

    // ---- wave64 reduction, lexicographic (val desc, idx asc) ----
    #pragma unroll
    for (int off = 32; off > 0; off >>= 1) {
        float ov = __shfl_down(bestv, (unsigned)off);
        int   oi = __shfl_down(besti, (unsigned)off);
        if (ov > bestv || (ov == bestv && oi < besti)) { bestv = ov; besti = oi; }
    }

    // ---- cross-wave (4 waves) via LDS, then broadcast box + lam ----
    __shared__ float s_v[4];
    __shared__ int   s_i[4];
    __shared__ int   s_box;
    __shared__ float s_lam;

    const int wave = tid >> 6;
    const int lane = tid & 63;
    if (lane == 0) { s_v[wave] = bestv; s_i[wave] = besti; }
    __syncthreads();
    if (tid == 0) {
        float bv = s_v[0]; int bi = s_i[0];
        #pragma unroll
        for (int w = 1; w < 4; ++w) {
            if (s_v[w] > bv || (s_v[w] == bv && s_i[w] < bi)) { bv = s_v[w]; bi = s_i[w]; }
        }
        const int mi = bi / HH;
        const int mj = bi - mi * HH;          // ref uses H for both div and mod
        const int h1 = max(mi - 3, 0);
        const int h2 = min(mi + 3, HH - 1);
        const int w1 = max(mj - 3, 0);
        const int w2 = min(mj + 3, WW - 1);
        const int zeros = (h2 - h1) * (w2 - w1);   // box is [h1,h2) x [w1,w2)
        s_lam = (float)HW / (float)(HW - zeros);
        s_box = h1 | (h2 << 8) | (w1 << 16) | (w2 << 24);
    }
    __syncthreads();

    const float lam = s_lam;
    const int   box = s_box;
    const int h1 =  box        & 255;
    const int h2 = (box >> 8)  & 255;
    const int w1 = (box >> 16) & 255;
    const int w2 = (box >> 24) & 255;

    // ---- write: in-box -> 0, else x*lam ----
    #pragma unroll
    for (int k = 0; k < 4; ++k) {
        int i = tid + k * BLK;
        if (i < NV4) {
            const float4 f = v[k];
            const int base = i * 4;
            float r[4] = { f.x, f.y, f.z, f.w };
            float4 o;
            float* op = (float*)&o;
            #pragma unroll
            for (int j = 0; j < 4; ++j) {
                const int e   = base + j;
                const int row = e / WW;          // const div -> magic mul
                const int col = e - row * WW;
                const bool inbox = (row >= h1) & (row < h2) & (col >= w1) & (col < w2);
                op[j] = inbox ? 0.0f : r[j] * lam;
            }
            xout[i] = o;
        }
    }
}

extern "C" void kernel_launch(void* const* d_in, const int* in_sizes, int n_in,
                              void* d_out, int out_size, void* d_ws, size_t ws_size,
                              hipStream_t stream) {
    const float* x = (const float*)d_in[0];
    const int*   T = (const int*)d_in[1];
    float*     out = (float*)d_out;
    const int channels = in_sizes[0] / HW;   // B*C = 16384
    local_mask_kernel<<<channels, BLK, 0, stream>>>(x, T, out);
}